// Round 1
// baseline (6180.788 us; speedup 1.0000x reference)
//
#include <hip/hip_runtime.h>

// ---------------------------------------------------------------------------
// Seq2seq stacked LSTM (encoder 120 steps + recursive decoder 120 steps).
// SEQ=120, BATCH=2048, INPUT=6, HID=64, LAYERS=4, TARGET=120.
//
// Strategy: batch elements are fully independent -> one wave (64 lanes) per
// batch element, lane j owns gate quad (i,f,g,o) of hidden column j.
// c-state in registers, h-state in a per-wave LDS row (broadcast reads).
// No __syncthreads anywhere. Weights repacked by a prep kernel into
// WQ[k][j][quad] so each lane loads its 4 gate weights as one float4.
// ---------------------------------------------------------------------------

#define S_LEN 120
#define BATCH 2048
#define NIN   6
#define H     64
#define NL    4
#define TLEN  120

#define ROWS0 (NIN + H)              // 70  rows for layer 0 (x part + h part)
#define ROWSL (2 * H)                // 128 rows for layers 1..3
#define ROWS_HALF (ROWS0 + 3 * ROWSL)  // 454 rows per enc/dec half
#define WQ_TOTAL (2 * ROWS_HALF * 256) // total floats in repacked weights

// ---------------------------------------------------------------------------
// Weight repack: WQ[half][row k][j][q] = W[g = q*64 + j][k-part]
//   layer0 rows: k in [0,6) -> Wih0[g][k]; k in [6,70) -> Whh[0][g][k-6]
//   layer l>=1 rows (base 70+(l-1)*128): r<64 -> Wih[l-1][g][r]; else Whh[l][g][r-64]
// ---------------------------------------------------------------------------
__global__ void prep_weights(const float* __restrict__ eWih0,
                             const float* __restrict__ eWih,
                             const float* __restrict__ eWhh,
                             const float* __restrict__ dWih0,
                             const float* __restrict__ dWih,
                             const float* __restrict__ dWhh,
                             float* __restrict__ wq) {
  int idx = blockIdx.x * blockDim.x + threadIdx.x;
  if (idx >= WQ_TOTAL) return;
  const int half = idx / (ROWS_HALF * 256);
  const int rem  = idx - half * (ROWS_HALF * 256);
  const int k    = rem >> 8;      // row
  const int col  = rem & 255;     // j*4 + q
  const int j    = col >> 2;
  const int q    = col & 3;
  const int g    = q * 64 + j;
  const float* Wi0 = half ? dWih0 : eWih0;
  const float* Wi  = half ? dWih  : eWih;
  const float* Wh  = half ? dWhh  : eWhh;
  float v;
  if (k < ROWS0) {
    if (k < NIN) v = Wi0[g * NIN + k];
    else         v = Wh[g * H + (k - NIN)];          // layer 0 Whh
  } else {
    const int kk = k - ROWS0;
    const int l  = kk / ROWSL + 1;                   // 1..3
    const int r  = kk - (l - 1) * ROWSL;
    if (r < H) v = Wi[((l - 1) * 256 + g) * H + r];
    else       v = Wh[(l * 256 + g) * H + (r - H)];
  }
  wq[idx] = v;
}

// ---------------------------------------------------------------------------
// device helpers
// ---------------------------------------------------------------------------
__device__ __forceinline__ float sigf(float x) { return 1.0f / (1.0f + __expf(-x)); }
// tanh via exp: exact at the extremes (exp->inf gives 1, exp->0 gives -1)
__device__ __forceinline__ float tanh_fast(float x) {
  float e = __expf(2.0f * x);
  return 1.0f - 2.0f / (e + 1.0f);
}

__device__ __forceinline__ void fma4(float4& a, float xk, const float4 w) {
  a.x = fmaf(xk, w.x, a.x);
  a.y = fmaf(xk, w.y, a.y);
  a.z = fmaf(xk, w.z, a.z);
  a.w = fmaf(xk, w.w, a.w);
}

__device__ __forceinline__ float gates_finish(float4 a, float& cst) {
  float gi = sigf(a.x);
  float gf = sigf(a.y);
  float gg = tanh_fast(a.z);
  float go = sigf(a.w);
  cst = fmaf(gf, cst, gi * gg);
  return go * tanh_fast(cst);
}

// LSTM cell for layers 1..3: input = 64-wide LDS row (broadcast), recurrent h row.
__device__ __forceinline__ float cell_h(const float4* __restrict__ wq4,
                                        const float* __restrict__ inrow,
                                        const float* __restrict__ hrow,
                                        const float4 bias, float& cst, const int lane) {
  float4 a = bias;
  #pragma unroll 4
  for (int k = 0; k < H; k += 4) {
    const float4 hk = *(const float4*)(inrow + k);
    const float4 w0 = wq4[(k + 0) * 64 + lane];
    const float4 w1 = wq4[(k + 1) * 64 + lane];
    const float4 w2 = wq4[(k + 2) * 64 + lane];
    const float4 w3 = wq4[(k + 3) * 64 + lane];
    fma4(a, hk.x, w0); fma4(a, hk.y, w1); fma4(a, hk.z, w2); fma4(a, hk.w, w3);
  }
  const float4* wh = wq4 + H * 64;
  #pragma unroll 4
  for (int k = 0; k < H; k += 4) {
    const float4 hk = *(const float4*)(hrow + k);
    const float4 w0 = wh[(k + 0) * 64 + lane];
    const float4 w1 = wh[(k + 1) * 64 + lane];
    const float4 w2 = wh[(k + 2) * 64 + lane];
    const float4 w3 = wh[(k + 3) * 64 + lane];
    fma4(a, hk.x, w0); fma4(a, hk.y, w1); fma4(a, hk.z, w2); fma4(a, hk.w, w3);
  }
  return gates_finish(a, cst);
}

// Layer-0 cell: 6 scalar inputs (lane-uniform regs) + recurrent h row.
__device__ __forceinline__ float cell_x(const float4* __restrict__ wq4,
                                        float x0, float x1, float x2,
                                        float x3, float x4, float x5,
                                        const float* __restrict__ hrow,
                                        const float4 bias, float& cst, const int lane) {
  float4 a = bias;
  fma4(a, x0, wq4[0 * 64 + lane]);
  fma4(a, x1, wq4[1 * 64 + lane]);
  fma4(a, x2, wq4[2 * 64 + lane]);
  fma4(a, x3, wq4[3 * 64 + lane]);
  fma4(a, x4, wq4[4 * 64 + lane]);
  fma4(a, x5, wq4[5 * 64 + lane]);
  const float4* wh = wq4 + NIN * 64;
  #pragma unroll 4
  for (int k = 0; k < H; k += 4) {
    const float4 hk = *(const float4*)(hrow + k);
    const float4 w0 = wh[(k + 0) * 64 + lane];
    const float4 w1 = wh[(k + 1) * 64 + lane];
    const float4 w2 = wh[(k + 2) * 64 + lane];
    const float4 w3 = wh[(k + 3) * 64 + lane];
    fma4(a, hk.x, w0); fma4(a, hk.y, w1); fma4(a, hk.z, w2); fma4(a, hk.w, w3);
  }
  return gates_finish(a, cst);
}

// ---------------------------------------------------------------------------
// Main persistent kernel: 256 blocks x 512 threads; wave w of block handles
// batch element b = blockIdx*8 + w through the entire enc+dec sequence.
// ---------------------------------------------------------------------------
__global__ void __launch_bounds__(512, 2)
lstm_main(const float* __restrict__ X,
          const float* __restrict__ encb,
          const float* __restrict__ decb,
          const float* __restrict__ linW,
          const float* __restrict__ linb,
          const float4* __restrict__ WQ,
          float* __restrict__ out) {
  __shared__ float hbuf[NL][8][H];
  const int tid  = threadIdx.x;
  const int w    = tid >> 6;
  const int lane = tid & 63;
  const int b    = blockIdx.x * 8 + w;
  const int bg   = __builtin_amdgcn_readfirstlane(b);  // wave-uniform -> SGPR

  // biases: quad (i,f,g,o) per lane, per layer, enc + dec
  float4 be[NL], bd[NL];
  #pragma unroll
  for (int l = 0; l < NL; l++) {
    be[l] = make_float4(encb[l * 256 + lane],       encb[l * 256 + 64 + lane],
                        encb[l * 256 + 128 + lane], encb[l * 256 + 192 + lane]);
    bd[l] = make_float4(decb[l * 256 + lane],       decb[l * 256 + 64 + lane],
                        decb[l * 256 + 128 + lane], decb[l * 256 + 192 + lane]);
  }

  float c0 = 0.f, c1 = 0.f, c2 = 0.f, c3 = 0.f;
  float* hb0 = &hbuf[0][w][0];
  float* hb1 = &hbuf[1][w][0];
  float* hb2 = &hbuf[2][w][0];
  float* hb3 = &hbuf[3][w][0];
  hb0[lane] = 0.f; hb1[lane] = 0.f; hb2[lane] = 0.f; hb3[lane] = 0.f;

  const float4* WE0 = WQ;
  const float4* WE1 = WQ + ROWS0 * 64;
  const float4* WE2 = WQ + (ROWS0 + ROWSL) * 64;
  const float4* WE3 = WQ + (ROWS0 + 2 * ROWSL) * 64;
  const float4* WD0 = WQ + ROWS_HALF * 64;
  const float4* WD1 = WD0 + ROWS0 * 64;
  const float4* WD2 = WD0 + (ROWS0 + ROWSL) * 64;
  const float4* WD3 = WD0 + (ROWS0 + 2 * ROWSL) * 64;

  // ------------------------------- encoder --------------------------------
  #pragma unroll 1
  for (int t = 0; t < S_LEN; t++) {
    const float* xp = X + ((size_t)t * BATCH + bg) * NIN;
    float hn = cell_x(WE0, xp[0], xp[1], xp[2], xp[3], xp[4], xp[5],
                      hb0, be[0], c0, lane);
    hb0[lane] = hn;
    hn = cell_h(WE1, hb0, hb1, be[1], c1, lane); hb1[lane] = hn;
    hn = cell_h(WE2, hb1, hb2, be[2], c2, lane); hb2[lane] = hn;
    hn = cell_h(WE3, hb2, hb3, be[3], c3, lane); hb3[lane] = hn;
  }

  // ------------------------------- decoder --------------------------------
  const float* xl = X + ((size_t)(S_LEN - 1) * BATCH + bg) * NIN;
  float p0 = xl[0], p1 = xl[1], p2 = xl[2], p3 = xl[3], p4 = xl[4], p5 = xl[5];
  const float lw0 = linW[0 * H + lane], lw1 = linW[1 * H + lane],
              lw2 = linW[2 * H + lane], lw3 = linW[3 * H + lane],
              lw4 = linW[4 * H + lane], lw5 = linW[5 * H + lane];
  const float lb0 = linb[0], lb1 = linb[1], lb2 = linb[2],
              lb3 = linb[3], lb4 = linb[4], lb5 = linb[5];

  #pragma unroll 1
  for (int t = 0; t < TLEN; t++) {
    float hn = cell_x(WD0, p0, p1, p2, p3, p4, p5, hb0, bd[0], c0, lane);
    hb0[lane] = hn;
    hn = cell_h(WD1, hb0, hb1, bd[1], c1, lane); hb1[lane] = hn;
    hn = cell_h(WD2, hb1, hb2, bd[2], c2, lane); hb2[lane] = hn;
    hn = cell_h(WD3, hb2, hb3, bd[3], c3, lane); hb3[lane] = hn;

    // output projection: out[i] = sum_j h3[j] * linW[i][j] + linb[i]
    float v0 = hn * lw0, v1 = hn * lw1, v2 = hn * lw2,
          v3 = hn * lw3, v4 = hn * lw4, v5 = hn * lw5;
    #pragma unroll
    for (int off = 32; off; off >>= 1) {
      v0 += __shfl_xor(v0, off);
      v1 += __shfl_xor(v1, off);
      v2 += __shfl_xor(v2, off);
      v3 += __shfl_xor(v3, off);
      v4 += __shfl_xor(v4, off);
      v5 += __shfl_xor(v5, off);
    }
    p0 = v0 + lb0; p1 = v1 + lb1; p2 = v2 + lb2;
    p3 = v3 + lb3; p4 = v4 + lb4; p5 = v5 + lb5;
    if (lane == 0) {
      float* op = out + ((size_t)t * BATCH + bg) * NIN;
      op[0] = p0; op[1] = p1; op[2] = p2; op[3] = p3; op[4] = p4; op[5] = p5;
    }
  }
}

// ---------------------------------------------------------------------------
extern "C" void kernel_launch(void* const* d_in, const int* in_sizes, int n_in,
                              void* d_out, int out_size, void* d_ws, size_t ws_size,
                              hipStream_t stream) {
  const float* X     = (const float*)d_in[0];
  const float* eWih0 = (const float*)d_in[1];
  const float* eWih  = (const float*)d_in[2];
  const float* eWhh  = (const float*)d_in[3];
  const float* eb    = (const float*)d_in[4];
  const float* dWih0 = (const float*)d_in[5];
  const float* dWih  = (const float*)d_in[6];
  const float* dWhh  = (const float*)d_in[7];
  const float* db    = (const float*)d_in[8];
  const float* lW    = (const float*)d_in[9];
  const float* lb    = (const float*)d_in[10];

  float* wq = (float*)d_ws;  // WQ_TOTAL floats (~930 KB) in workspace

  prep_weights<<<(WQ_TOTAL + 255) / 256, 256, 0, stream>>>(
      eWih0, eWih, eWhh, dWih0, dWih, dWhh, wq);

  lstm_main<<<BATCH / 8, 512, 0, stream>>>(
      X, eb, db, lW, lb, (const float4*)wq, (float*)d_out);
}

// Round 2
// 5537.292 us; speedup vs baseline: 1.1162x; 1.1162x over previous
//
#include <hip/hip_runtime.h>

// ---------------------------------------------------------------------------
// Seq2seq stacked LSTM. Round 2: L2-feed-bound fix.
//  - fp16 weights (RTN), fp32 inputs/accumulate via v_fma_mix
//  - NB=2 batch elements per wave (each weight fetch feeds 2 columns)
//  - 1024 waves (256 blocks x 256 thr), zero barriers, c-state in VGPRs
// ---------------------------------------------------------------------------

#define S_LEN 120
#define BATCH 2048
#define NIN   6
#define H     64
#define NL    4
#define TLEN  120

#define ROWS0 (NIN + H)               // 70 rows, layer 0 (x + h)
#define ROWSL (2 * H)                 // 128 rows, layers 1..3
#define ROWS_HALF (ROWS0 + 3 * ROWSL) // 454 rows per enc/dec half
#define PAIRS_HALF (ROWS_HALF / 2)    // 227 row-pairs
#define WQ_HALFS (2 * PAIRS_HALF * 64 * 8)  // fp16 element count (232448)

typedef __attribute__((ext_vector_type(8))) _Float16 half8;

__global__ void prep_weights(const float* __restrict__ eWih0,
                             const float* __restrict__ eWih,
                             const float* __restrict__ eWhh,
                             const float* __restrict__ dWih0,
                             const float* __restrict__ dWih,
                             const float* __restrict__ dWhh,
                             _Float16* __restrict__ wq) {
  int idx = blockIdx.x * blockDim.x + threadIdx.x;
  if (idx >= WQ_HALFS) return;
  const int s    = idx & 7;
  const int lane = (idx >> 3) & 63;
  const int t    = idx >> 9;
  const int p    = t % PAIRS_HALF;
  const int half = t / PAIRS_HALF;
  const int rip  = s >> 2;
  const int q    = s & 3;
  const int k    = 2 * p + rip;
  const int g    = (q << 6) + lane;
  const float* Wi0 = half ? dWih0 : eWih0;
  const float* Wi  = half ? dWih  : eWih;
  const float* Wh  = half ? dWhh  : eWhh;
  float v;
  if (k < ROWS0) {
    if (k < NIN) v = Wi0[g * NIN + k];
    else         v = Wh[g * H + (k - NIN)];          // layer 0 Whh
  } else {
    const int kk = k - ROWS0;
    const int l  = kk / ROWSL + 1;                   // 1..3
    const int r  = kk - (l - 1) * ROWSL;
    if (r < H) v = Wi[((l - 1) * 256 + g) * H + r];
    else       v = Wh[(l * 256 + g) * H + (r - H)];
  }
  wq[idx] = (_Float16)v;   // RTN
}

__device__ __forceinline__ float sigf(float x) { return 1.0f / (1.0f + __expf(-x)); }
__device__ __forceinline__ float tanh_fast(float x) {
  float e = __expf(2.0f * x);
  return 1.0f - 2.0f / (e + 1.0f);
}

__device__ __forceinline__ float gates_finish(float4 a, float& cst) {
  float gi = sigf(a.x);
  float gf = sigf(a.y);
  float gg = tanh_fast(a.z);
  float go = sigf(a.w);
  cst = fmaf(gf, cst, gi * gg);
  return go * tanh_fast(cst);
}

__device__ __forceinline__ void fma_pair(float4& a, float xe, float xo, const half8 w) {
  a.x = fmaf((float)w[0], xe, a.x);
  a.y = fmaf((float)w[1], xe, a.y);
  a.z = fmaf((float)w[2], xe, a.z);
  a.w = fmaf((float)w[3], xe, a.w);
  a.x = fmaf((float)w[4], xo, a.x);
  a.y = fmaf((float)w[5], xo, a.y);
  a.z = fmaf((float)w[6], xo, a.z);
  a.w = fmaf((float)w[7], xo, a.w);
}

__device__ __forceinline__ void seg64(const half8* __restrict__ w,
                                      const float* __restrict__ r0,
                                      const float* __restrict__ r1,
                                      float4& a0, float4& a1, const int lane) {
  #pragma unroll 4
  for (int k = 0; k < H; k += 4) {
    const float4 i0 = *(const float4*)(r0 + k);
    const float4 i1 = *(const float4*)(r1 + k);
    const half8 wa = w[((k >> 1) + 0) * 64 + lane];
    const half8 wb = w[((k >> 1) + 1) * 64 + lane];
    fma_pair(a0, i0.x, i0.y, wa);
    fma_pair(a1, i1.x, i1.y, wa);
    fma_pair(a0, i0.z, i0.w, wb);
    fma_pair(a1, i1.z, i1.w, wb);
  }
}

__device__ __forceinline__ float2 cell_h2(const half8* __restrict__ wq,
                                          const float* __restrict__ in0,
                                          const float* __restrict__ in1,
                                          const float* __restrict__ h0,
                                          const float* __restrict__ h1,
                                          const float4 bias,
                                          float& c0, float& c1, const int lane) {
  float4 a0 = bias, a1 = bias;
  seg64(wq, in0, in1, a0, a1, lane);
  seg64(wq + 32 * 64, h0, h1, a0, a1, lane);
  float2 r;
  r.x = gates_finish(a0, c0);
  r.y = gates_finish(a1, c1);
  return r;
}

__device__ __forceinline__ float2 cell_x2(const half8* __restrict__ wq,
                                          float x00, float x01, float x02,
                                          float x03, float x04, float x05,
                                          float x10, float x11, float x12,
                                          float x13, float x14, float x15,
                                          const float* __restrict__ h0,
                                          const float* __restrict__ h1,
                                          const float4 bias,
                                          float& c0, float& c1, const int lane) {
  float4 a0 = bias, a1 = bias;
  const half8 w0 = wq[0 * 64 + lane];
  const half8 w1 = wq[1 * 64 + lane];
  const half8 w2 = wq[2 * 64 + lane];
  fma_pair(a0, x00, x01, w0); fma_pair(a1, x10, x11, w0);
  fma_pair(a0, x02, x03, w1); fma_pair(a1, x12, x13, w1);
  fma_pair(a0, x04, x05, w2); fma_pair(a1, x14, x15, w2);
  seg64(wq + 3 * 64, h0, h1, a0, a1, lane);
  float2 r;
  r.x = gates_finish(a0, c0);
  r.y = gates_finish(a1, c1);
  return r;
}

__global__ void __launch_bounds__(256, 1)
lstm_main(const float* __restrict__ X,
          const float* __restrict__ encb,
          const float* __restrict__ decb,
          const float* __restrict__ linW,
          const float* __restrict__ linb,
          const half8* __restrict__ WQ,
          float* __restrict__ out) {
  __shared__ float hbuf[NL][4][2][H];   // 8 KB
  const int tid  = threadIdx.x;
  const int w    = tid >> 6;
  const int lane = tid & 63;
  const int W    = blockIdx.x * 4 + w;
  const int b0   = __builtin_amdgcn_readfirstlane(2 * W);
  const int b1   = b0 + 1;

  float4 be[NL], bd[NL];
  #pragma unroll
  for (int l = 0; l < NL; l++) {
    be[l] = make_float4(encb[l * 256 + lane],       encb[l * 256 + 64 + lane],
                        encb[l * 256 + 128 + lane], encb[l * 256 + 192 + lane]);
    bd[l] = make_float4(decb[l * 256 + lane],       decb[l * 256 + 64 + lane],
                        decb[l * 256 + 128 + lane], decb[l * 256 + 192 + lane]);
  }

  float c00 = 0.f, c01 = 0.f, c10 = 0.f, c11 = 0.f,
        c20 = 0.f, c21 = 0.f, c30 = 0.f, c31 = 0.f;

  float* h00 = &hbuf[0][w][0][0]; float* h01 = &hbuf[0][w][1][0];
  float* h10 = &hbuf[1][w][0][0]; float* h11 = &hbuf[1][w][1][0];
  float* h20 = &hbuf[2][w][0][0]; float* h21 = &hbuf[2][w][1][0];
  float* h30 = &hbuf[3][w][0][0]; float* h31 = &hbuf[3][w][1][0];
  h00[lane] = 0.f; h01[lane] = 0.f; h10[lane] = 0.f; h11[lane] = 0.f;
  h20[lane] = 0.f; h21[lane] = 0.f; h30[lane] = 0.f; h31[lane] = 0.f;

  const half8* WE0 = WQ;
  const half8* WE1 = WQ + 35 * 64;
  const half8* WE2 = WQ + (35 + 64) * 64;
  const half8* WE3 = WQ + (35 + 128) * 64;
  const half8* WD0 = WQ + PAIRS_HALF * 64;
  const half8* WD1 = WD0 + 35 * 64;
  const half8* WD2 = WD0 + (35 + 64) * 64;
  const half8* WD3 = WD0 + (35 + 128) * 64;

  #pragma unroll 1
  for (int t = 0; t < S_LEN; t++) {
    const float* xp0 = X + ((size_t)t * BATCH + b0) * NIN;
    const float* xp1 = X + ((size_t)t * BATCH + b1) * NIN;
    float2 hn = cell_x2(WE0, xp0[0], xp0[1], xp0[2], xp0[3], xp0[4], xp0[5],
                        xp1[0], xp1[1], xp1[2], xp1[3], xp1[4], xp1[5],
                        h00, h01, be[0], c00, c01, lane);
    h00[lane] = hn.x; h01[lane] = hn.y;
    hn = cell_h2(WE1, h00, h01, h10, h11, be[1], c10, c11, lane);
    h10[lane] = hn.x; h11[lane] = hn.y;
    hn = cell_h2(WE2, h10, h11, h20, h21, be[2], c20, c21, lane);
    h20[lane] = hn.x; h21[lane] = hn.y;
    hn = cell_h2(WE3, h20, h21, h30, h31, be[3], c30, c31, lane);
    h30[lane] = hn.x; h31[lane] = hn.y;
  }

  const float* xl0 = X + ((size_t)(S_LEN - 1) * BATCH + b0) * NIN;
  const float* xl1 = X + ((size_t)(S_LEN - 1) * BATCH + b1) * NIN;
  float p00 = xl0[0], p01 = xl0[1], p02 = xl0[2],
        p03 = xl0[3], p04 = xl0[4], p05 = xl0[5];
  float p10 = xl1[0], p11 = xl1[1], p12 = xl1[2],
        p13 = xl1[3], p14 = xl1[4], p15 = xl1[5];

  const float lw0 = linW[0 * H + lane], lw1 = linW[1 * H + lane],
              lw2 = linW[2 * H + lane], lw3 = linW[3 * H + lane],
              lw4 = linW[4 * H + lane], lw5 = linW[5 * H + lane];
  const float lb0 = linb[0], lb1 = linb[1], lb2 = linb[2],
              lb3 = linb[3], lb4 = linb[4], lb5 = linb[5];

  #pragma unroll 1
  for (int t = 0; t < TLEN; t++) {
    float2 hn = cell_x2(WD0, p00, p01, p02, p03, p04, p05,
                        p10, p11, p12, p13, p14, p15,
                        h00, h01, bd[0], c00, c01, lane);
    h00[lane] = hn.x; h01[lane] = hn.y;
    hn = cell_h2(WD1, h00, h01, h10, h11, bd[1], c10, c11, lane);
    h10[lane] = hn.x; h11[lane] = hn.y;
    hn = cell_h2(WD2, h10, h11, h20, h21, bd[2], c20, c21, lane);
    h20[lane] = hn.x; h21[lane] = hn.y;
    hn = cell_h2(WD3, h20, h21, h30, h31, bd[3], c30, c31, lane);
    h30[lane] = hn.x; h31[lane] = hn.y;

    float v00 = hn.x * lw0, v01 = hn.x * lw1, v02 = hn.x * lw2,
          v03 = hn.x * lw3, v04 = hn.x * lw4, v05 = hn.x * lw5;
    float v10 = hn.y * lw0, v11 = hn.y * lw1, v12 = hn.y * lw2,
          v13 = hn.y * lw3, v14 = hn.y * lw4, v15 = hn.y * lw5;
    #pragma unroll
    for (int off = 32; off; off >>= 1) {
      v00 += __shfl_xor(v00, off); v01 += __shfl_xor(v01, off);
      v02 += __shfl_xor(v02, off); v03 += __shfl_xor(v03, off);
      v04 += __shfl_xor(v04, off); v05 += __shfl_xor(v05, off);
      v10 += __shfl_xor(v10, off); v11 += __shfl_xor(v11, off);
      v12 += __shfl_xor(v12, off); v13 += __shfl_xor(v13, off);
      v14 += __shfl_xor(v14, off); v15 += __shfl_xor(v15, off);
    }
    p00 = v00 + lb0; p01 = v01 + lb1; p02 = v02 + lb2;
    p03 = v03 + lb3; p04 = v04 + lb4; p05 = v05 + lb5;
    p10 = v10 + lb0; p11 = v11 + lb1; p12 = v12 + lb2;
    p13 = v13 + lb3; p14 = v14 + lb4; p15 = v15 + lb5;
    if (lane == 0) {
      float* op = out + ((size_t)t * BATCH + b0) * NIN;
      op[0] = p00; op[1] = p01; op[2] = p02;
      op[3] = p03; op[4] = p04; op[5] = p05;
    }
    if (lane == 1) {
      float* op = out + ((size_t)t * BATCH + b1) * NIN;
      op[0] = p10; op[1] = p11; op[2] = p12;
      op[3] = p13; op[4] = p14; op[5] = p15;
    }
  }
}

extern "C" void kernel_launch(void* const* d_in, const int* in_sizes, int n_in,
                              void* d_out, int out_size, void* d_ws, size_t ws_size,
                              hipStream_t stream) {
  const float* X     = (const float*)d_in[0];
  const float* eWih0 = (const float*)d_in[1];
  const float* eWih  = (const float*)d_in[2];
  const float* eWhh  = (const float*)d_in[3];
  const float* eb    = (const float*)d_in[4];
  const float* dWih0 = (const float*)d_in[5];
  const float* dWih  = (const float*)d_in[6];
  const float* dWhh  = (const float*)d_in[7];
  const float* db    = (const float*)d_in[8];
  const float* lW    = (const float*)d_in[9];
  const float* lb    = (const float*)d_in[10];

  _Float16* wq = (_Float16*)d_ws;   // 465 KB fp16 weight pack in workspace

  prep_weights<<<(WQ_HALFS + 255) / 256, 256, 0, stream>>>(
      eWih0, eWih, eWhh, dWih0, dWih, dWhh, wq);

  lstm_main<<<256, 256, 0, stream>>>(
      X, eb, db, lW, lb, (const half8*)wq, (float*)d_out);
}

// Round 3
// 651.503 us; speedup vs baseline: 9.4870x; 8.4993x over previous
//
#include <hip/hip_runtime.h>

// ---------------------------------------------------------------------------
// Round 3: MFMA reformulation.
// Block = 16 batch elements, 4 waves; wave wv owns hidden cols [16wv,16wv+16).
// Gates via v_mfma_f32_16x16x32_f16; weights register-resident (60 frags);
// h state ping-pongs through LDS (fp16); c state in VGPRs; elementwise is
// lane-local because gate tiles (i,f,g,o) sit at N-stride 64 = same lane.
// ---------------------------------------------------------------------------

#define S_LEN 120
#define BATCH 2048
#define NIN   6
#define H     64
#define NL    4
#define TLEN  120

#define HPAD 72            // Hb row stride in halves (144 B: 16B-aligned, 2-way banks)
#define XPAD 40            // Xb row stride in halves (80 B: 16B-aligned, 2-way banks)

#define FRAGS_HALF 60      // 12 (layer0: 3 ktiles x 4 ntiles) + 3*16
#define PACK_H8    (2 * FRAGS_HALF * 4 * 64)   // h8 units for enc+dec gate weights
#define PROJ_H8    (2 * 64)                    // 2 frags for linW
#define NPACK      ((PACK_H8 + PROJ_H8) * 8)   // total fp16 elements (246784)

typedef _Float16 h8   __attribute__((ext_vector_type(8)));
typedef float    f32x4 __attribute__((ext_vector_type(4)));

// ---------------------------------------------------------------------------
// Weight pack, B-fragment layout for v_mfma_f32_16x16x32_f16:
// B[k][n] per lane: n = lane&15, k = (lane>>4)*8 + j, j in [0,8).
// Fragment index f per half: layer0: f = q*3 + kt (kt0 = x-tile, kt1/2 = rec);
// layer l>=1 (base 12+16(l-1)): f = base + q*4 + kt (kt0/1 = input, kt2/3 = rec).
// Gate row g = q*64 + wv*16 + (lane&15).  Address: ((half*60+f)*4+wv)*64+lane.
// ---------------------------------------------------------------------------
__global__ void prep_weights(const float* __restrict__ eWih0,
                             const float* __restrict__ eWih,
                             const float* __restrict__ eWhh,
                             const float* __restrict__ dWih0,
                             const float* __restrict__ dWih,
                             const float* __restrict__ dWhh,
                             const float* __restrict__ linW,
                             _Float16* __restrict__ wq) {
  int idx = blockIdx.x * blockDim.x + threadIdx.x;
  if (idx >= NPACK) return;
  if (idx >= PACK_H8 * 8) {
    // projection frags: linW[n][k], n = lane&15 (<6 else 0)
    int p    = idx - PACK_H8 * 8;
    int j    = p & 7;
    int lane = (p >> 3) & 63;
    int kt   = p >> 9;                     // 0,1
    int n    = lane & 15;
    int k    = kt * 32 + (lane >> 4) * 8 + j;
    wq[idx] = (_Float16)((n < NIN) ? linW[n * H + k] : 0.0f);
    return;
  }
  const int j    = idx & 7;
  const int lane = (idx >> 3) & 63;
  const int wv   = (idx >> 9) & 3;
  const int fh   = idx >> 11;
  const int f    = fh % FRAGS_HALF;
  const int half = fh / FRAGS_HALF;
  const float* Wi0 = half ? dWih0 : eWih0;
  const float* Wi  = half ? dWih  : eWih;
  const float* Wh  = half ? dWhh  : eWhh;

  int l, q, kt;
  if (f < 12) { l = 0; q = f / 3; kt = f % 3; }
  else        { int ff = f - 12; l = 1 + ff / 16; ff %= 16; q = ff / 4; kt = ff % 4; }

  const int g    = q * 64 + wv * 16 + (lane & 15);
  const int k_in = (lane >> 4) * 8 + j;          // k within the 32-wide tile
  float v;
  if (l == 0) {
    if (kt == 0) v = (k_in < NIN) ? Wi0[g * NIN + k_in] : 0.0f;
    else         v = Wh[g * H + (kt - 1) * 32 + k_in];          // layer0 Whh
  } else {
    if (kt < 2) v = Wi[((l - 1) * 256 + g) * H + kt * 32 + k_in];
    else        v = Wh[(l * 256 + g) * H + (kt - 2) * 32 + k_in];
  }
  wq[idx] = (_Float16)v;
}

// ---------------------------------------------------------------------------
__device__ __forceinline__ float rcpf(float x) { return __builtin_amdgcn_rcpf(x); }
__device__ __forceinline__ float sigf(float x) { return rcpf(1.0f + __expf(-x)); }
__device__ __forceinline__ float tanhf_(float x) {
  float e = __expf(2.0f * x);
  return 1.0f - 2.0f * rcpf(e + 1.0f);
}
__device__ __forceinline__ f32x4 mf(h8 a, h8 b, f32x4 c) {
  return __builtin_amdgcn_mfma_f32_16x16x32_f16(a, b, c, 0, 0, 0);
}

// elementwise LSTM update from 4 gate-tile accumulators; writes h (fp16) to LDS
__device__ __forceinline__ void cell_ew(f32x4 g0, f32x4 g1, f32x4 g2, f32x4 g3,
                                        f32x4& c, _Float16* outbuf,
                                        int quad, int r16, int wv) {
  #pragma unroll
  for (int r = 0; r < 4; r++) {
    float gi = sigf(g0[r]);
    float gf = sigf(g1[r]);
    float gg = tanhf_(g2[r]);
    float go = sigf(g3[r]);
    c[r] = fmaf(gf, c[r], gi * gg);
    float hnew = go * tanhf_(c[r]);
    outbuf[(quad * 4 + r) * HPAD + wv * 16 + r16] = (_Float16)hnew;
  }
}

// layers 1..3: input h (this t, layer l-1) + recurrent h (prev t, layer l)
__device__ __forceinline__ void layerH(const h8* wl, const _Float16* inbuf,
                                       const _Float16* recbuf, _Float16* outbuf,
                                       const float* bias, f32x4& c,
                                       int quad, int r16, int wv) {
  const h8 ai0 = *(const h8*)(inbuf  + r16 * HPAD +      quad * 8);
  const h8 ai1 = *(const h8*)(inbuf  + r16 * HPAD + 32 + quad * 8);
  const h8 ar0 = *(const h8*)(recbuf + r16 * HPAD +      quad * 8);
  const h8 ar1 = *(const h8*)(recbuf + r16 * HPAD + 32 + quad * 8);
  f32x4 g0 = {bias[0], bias[0], bias[0], bias[0]};
  f32x4 g1 = {bias[1], bias[1], bias[1], bias[1]};
  f32x4 g2 = {bias[2], bias[2], bias[2], bias[2]};
  f32x4 g3 = {bias[3], bias[3], bias[3], bias[3]};
  g0 = mf(ai0, wl[0],  g0); g1 = mf(ai0, wl[4],  g1);
  g2 = mf(ai0, wl[8],  g2); g3 = mf(ai0, wl[12], g3);
  g0 = mf(ai1, wl[1],  g0); g1 = mf(ai1, wl[5],  g1);
  g2 = mf(ai1, wl[9],  g2); g3 = mf(ai1, wl[13], g3);
  g0 = mf(ar0, wl[2],  g0); g1 = mf(ar0, wl[6],  g1);
  g2 = mf(ar0, wl[10], g2); g3 = mf(ar0, wl[14], g3);
  g0 = mf(ar1, wl[3],  g0); g1 = mf(ar1, wl[7],  g1);
  g2 = mf(ar1, wl[11], g2); g3 = mf(ar1, wl[15], g3);
  cell_ew(g0, g1, g2, g3, c, outbuf, quad, r16, wv);
}

// layer 0: x-tile (32-wide, 6 real cols) + recurrent h
__device__ __forceinline__ void layer0(const h8* wl, const _Float16* xbuf,
                                       const _Float16* recbuf, _Float16* outbuf,
                                       const float* bias, f32x4& c,
                                       int quad, int r16, int wv) {
  const h8 ax  = *(const h8*)(xbuf   + r16 * XPAD +      quad * 8);
  const h8 ar0 = *(const h8*)(recbuf + r16 * HPAD +      quad * 8);
  const h8 ar1 = *(const h8*)(recbuf + r16 * HPAD + 32 + quad * 8);
  f32x4 g0 = {bias[0], bias[0], bias[0], bias[0]};
  f32x4 g1 = {bias[1], bias[1], bias[1], bias[1]};
  f32x4 g2 = {bias[2], bias[2], bias[2], bias[2]};
  f32x4 g3 = {bias[3], bias[3], bias[3], bias[3]};
  g0 = mf(ax,  wl[0],  g0); g1 = mf(ax,  wl[3],  g1);
  g2 = mf(ax,  wl[6],  g2); g3 = mf(ax,  wl[9],  g3);
  g0 = mf(ar0, wl[1],  g0); g1 = mf(ar0, wl[4],  g1);
  g2 = mf(ar0, wl[7],  g2); g3 = mf(ar0, wl[10], g3);
  g0 = mf(ar1, wl[2],  g0); g1 = mf(ar1, wl[5],  g1);
  g2 = mf(ar1, wl[8],  g2); g3 = mf(ar1, wl[11], g3);
  cell_ew(g0, g1, g2, g3, c, outbuf, quad, r16, wv);
}

// ---------------------------------------------------------------------------
// Main kernel: 128 blocks x 256 threads (4 waves), block b owns batch
// [16b, 16b+16). Ping-pong Hb by timestep parity -> no read/write hazards,
// one barrier per layer.
// ---------------------------------------------------------------------------
__global__ void __launch_bounds__(256, 1)
lstm_main(const float* __restrict__ X,
          const float* __restrict__ encb,
          const float* __restrict__ decb,
          const float* __restrict__ linb,
          const h8* __restrict__ WQ,
          float* __restrict__ out) {
  __shared__ _Float16 Hb[NL][2][16][HPAD];   // 18432 B
  __shared__ _Float16 Xb[16][XPAD];          // 1280 B (cols 6..31 stay zero)

  const int tid  = threadIdx.x;
  const int wv   = tid >> 6;
  const int lane = tid & 63;
  const int quad = lane >> 4;
  const int r16  = lane & 15;
  const int bbase = blockIdx.x * 16;

  // zero all LDS (h0 = c0 = 0; Xb pad cols must be 0)
  {
    float* p = (float*)&Hb[0][0][0][0];
    for (int i = tid; i < (int)(NL * 2 * 16 * HPAD / 2); i += 256) p[i] = 0.0f;
    float* px = (float*)&Xb[0][0];
    for (int i = tid; i < (int)(16 * XPAD / 2); i += 256) px[i] = 0.0f;
  }

  // biases: 4 gate values per layer (enc first; dec loaded after enc loop)
  float bl[NL][4];
  #pragma unroll
  for (int l = 0; l < NL; l++)
    #pragma unroll
    for (int q = 0; q < 4; q++)
      bl[l][q] = encb[l * 256 + q * 64 + wv * 16 + r16];

  // projection fragments + bias (wave 0 only)
  h8 lwf0 = {}, lwf1 = {};
  float lbv = 0.0f;
  if (wv == 0) {
    lwf0 = WQ[PACK_H8 + lane];
    lwf1 = WQ[PACK_H8 + 64 + lane];
    lbv  = (r16 < NIN) ? linb[r16] : 0.0f;
  }

  // c-state: 4 rows per layer per lane
  f32x4 cs[NL];
  #pragma unroll
  for (int l = 0; l < NL; l++) cs[l] = (f32x4){0.f, 0.f, 0.f, 0.f};

  // encoder weights -> registers (60 frags = 240 VGPRs)
  h8 wr[FRAGS_HALF];
  #pragma unroll
  for (int f = 0; f < FRAGS_HALF; f++)
    wr[f] = WQ[(f * 4 + wv) * 64 + lane];

  __syncthreads();   // LDS zeroing visible

  // ------------------------------- encoder --------------------------------
  #pragma unroll 1
  for (int t = 0; t < S_LEN; t++) {
    const int cur = t & 1, prv = cur ^ 1;
    if (tid < 96) {
      const int m = tid / NIN, i = tid - m * NIN;
      Xb[m][i] = (_Float16)X[((size_t)t * BATCH + bbase + m) * NIN + i];
    }
    __syncthreads();
    layer0(wr +  0, &Xb[0][0],        &Hb[0][prv][0][0], &Hb[0][cur][0][0],
           bl[0], cs[0], quad, r16, wv);
    __syncthreads();
    layerH(wr + 12, &Hb[0][cur][0][0], &Hb[1][prv][0][0], &Hb[1][cur][0][0],
           bl[1], cs[1], quad, r16, wv);
    __syncthreads();
    layerH(wr + 28, &Hb[1][cur][0][0], &Hb[2][prv][0][0], &Hb[2][cur][0][0],
           bl[2], cs[2], quad, r16, wv);
    __syncthreads();
    layerH(wr + 44, &Hb[2][cur][0][0], &Hb[3][prv][0][0], &Hb[3][cur][0][0],
           bl[3], cs[3], quad, r16, wv);
  }

  // switch to decoder weights + biases (Xb still holds x[S_LEN-1])
  #pragma unroll
  for (int f = 0; f < FRAGS_HALF; f++)
    wr[f] = WQ[((FRAGS_HALF + f) * 4 + wv) * 64 + lane];
  #pragma unroll
  for (int l = 0; l < NL; l++)
    #pragma unroll
    for (int q = 0; q < 4; q++)
      bl[l][q] = decb[l * 256 + q * 64 + wv * 16 + r16];

  // ------------------------------- decoder --------------------------------
  #pragma unroll 1
  for (int t = 0; t < TLEN; t++) {
    const int cur = (S_LEN + t) & 1, prv = cur ^ 1;
    __syncthreads();   // orders previous proj's Xb write before layer0 read
    layer0(wr +  0, &Xb[0][0],        &Hb[0][prv][0][0], &Hb[0][cur][0][0],
           bl[0], cs[0], quad, r16, wv);
    __syncthreads();
    layerH(wr + 12, &Hb[0][cur][0][0], &Hb[1][prv][0][0], &Hb[1][cur][0][0],
           bl[1], cs[1], quad, r16, wv);
    __syncthreads();
    layerH(wr + 28, &Hb[1][cur][0][0], &Hb[2][prv][0][0], &Hb[2][cur][0][0],
           bl[2], cs[2], quad, r16, wv);
    __syncthreads();
    layerH(wr + 44, &Hb[2][cur][0][0], &Hb[3][prv][0][0], &Hb[3][cur][0][0],
           bl[3], cs[3], quad, r16, wv);
    __syncthreads();   // h3 writes visible to projection

    if (wv == 0) {
      // out[m][n] = h3[m][:] @ linW[n][:] + linb[n]; feed back via Xb
      const _Float16* h3 = &Hb[3][cur][0][0];
      const h8 a0 = *(const h8*)(h3 + r16 * HPAD +      quad * 8);
      const h8 a1 = *(const h8*)(h3 + r16 * HPAD + 32 + quad * 8);
      f32x4 ap = {lbv, lbv, lbv, lbv};
      ap = mf(a0, lwf0, ap);
      ap = mf(a1, lwf1, ap);
      if (r16 < NIN) {
        #pragma unroll
        for (int r = 0; r < 4; r++) {
          const int m = quad * 4 + r;
          out[((size_t)t * BATCH + bbase + m) * NIN + r16] = ap[r];
          Xb[m][r16] = (_Float16)ap[r];
        }
      }
    }
  }
}

// ---------------------------------------------------------------------------
extern "C" void kernel_launch(void* const* d_in, const int* in_sizes, int n_in,
                              void* d_out, int out_size, void* d_ws, size_t ws_size,
                              hipStream_t stream) {
  const float* X     = (const float*)d_in[0];
  const float* eWih0 = (const float*)d_in[1];
  const float* eWih  = (const float*)d_in[2];
  const float* eWhh  = (const float*)d_in[3];
  const float* eb    = (const float*)d_in[4];
  const float* dWih0 = (const float*)d_in[5];
  const float* dWih  = (const float*)d_in[6];
  const float* dWhh  = (const float*)d_in[7];
  const float* db    = (const float*)d_in[8];
  const float* lW    = (const float*)d_in[9];
  const float* lb    = (const float*)d_in[10];

  _Float16* wq = (_Float16*)d_ws;   // ~483 KB pack in workspace

  prep_weights<<<(NPACK + 255) / 256, 256, 0, stream>>>(
      eWih0, eWih, eWhh, dWih0, dWih, dWhh, lW, wq);

  lstm_main<<<BATCH / 16, 256, 0, stream>>>(
      X, eb, db, lb, (const h8*)wq, (float*)d_out);
}

// Round 4
// 584.742 us; speedup vs baseline: 10.5701x; 1.1142x over previous
//
#include <hip/hip_runtime.h>

// ---------------------------------------------------------------------------
// Round 4: register-resident weights (per-layer arrays, constant indexing) +
// software-pipelined recurrent partials (bias + Whh*h_l[t-1] precomputed one
// interval after h_l[t-1] lands, reusing the same LDS A-fragment reads as the
// next layer's input). Critical interval = ds_read -> 1-2 MFMA -> elementwise
// -> ds_write -> barrier.
// ---------------------------------------------------------------------------

#define S_LEN 120
#define BATCH 2048
#define NIN   6
#define H     64
#define NL    4
#define TLEN  120

#define HPAD 72            // Hb row stride in halves
#define XPAD 40            // Xb row stride in halves

#define FRAGS_HALF 60      // 12 (layer0) + 3*16
#define PACK_H8    (2 * FRAGS_HALF * 4 * 64)
#define PROJ_H8    (2 * 64)
#define NPACK      ((PACK_H8 + PROJ_H8) * 8)

typedef _Float16 h8    __attribute__((ext_vector_type(8)));
typedef float    f32x4 __attribute__((ext_vector_type(4)));

// ---------------------------------------------------------------------------
// Weight pack (unchanged from round 3): B-fragment layout for 16x16x32 f16.
// layer0: f = q*3 + kt (kt0 = x-tile, kt1/2 = rec); layer l>=1 (base
// 12+16(l-1)): f = base + q*4 + kt (kt0/1 = input, kt2/3 = rec).
// ---------------------------------------------------------------------------
__global__ void prep_weights(const float* __restrict__ eWih0,
                             const float* __restrict__ eWih,
                             const float* __restrict__ eWhh,
                             const float* __restrict__ dWih0,
                             const float* __restrict__ dWih,
                             const float* __restrict__ dWhh,
                             const float* __restrict__ linW,
                             _Float16* __restrict__ wq) {
  int idx = blockIdx.x * blockDim.x + threadIdx.x;
  if (idx >= NPACK) return;
  if (idx >= PACK_H8 * 8) {
    int p    = idx - PACK_H8 * 8;
    int j    = p & 7;
    int lane = (p >> 3) & 63;
    int kt   = p >> 9;
    int n    = lane & 15;
    int k    = kt * 32 + (lane >> 4) * 8 + j;
    wq[idx] = (_Float16)((n < NIN) ? linW[n * H + k] : 0.0f);
    return;
  }
  const int j    = idx & 7;
  const int lane = (idx >> 3) & 63;
  const int wv   = (idx >> 9) & 3;
  const int fh   = idx >> 11;
  const int f    = fh % FRAGS_HALF;
  const int half = fh / FRAGS_HALF;
  const float* Wi0 = half ? dWih0 : eWih0;
  const float* Wi  = half ? dWih  : eWih;
  const float* Wh  = half ? dWhh  : eWhh;

  int l, q, kt;
  if (f < 12) { l = 0; q = f / 3; kt = f % 3; }
  else        { int ff = f - 12; l = 1 + ff / 16; ff %= 16; q = ff / 4; kt = ff % 4; }

  const int g    = q * 64 + wv * 16 + (lane & 15);
  const int k_in = (lane >> 4) * 8 + j;
  float v;
  if (l == 0) {
    if (kt == 0) v = (k_in < NIN) ? Wi0[g * NIN + k_in] : 0.0f;
    else         v = Wh[g * H + (kt - 1) * 32 + k_in];
  } else {
    if (kt < 2) v = Wi[((l - 1) * 256 + g) * H + kt * 32 + k_in];
    else        v = Wh[(l * 256 + g) * H + (kt - 2) * 32 + k_in];
  }
  wq[idx] = (_Float16)v;
}

// ---------------------------------------------------------------------------
__device__ __forceinline__ float rcpf(float x) { return __builtin_amdgcn_rcpf(x); }
__device__ __forceinline__ float sigf(float x) { return rcpf(1.0f + __expf(-x)); }
__device__ __forceinline__ float tanhf_(float x) {
  float e = __expf(2.0f * x);
  return 1.0f - 2.0f * rcpf(e + 1.0f);
}
__device__ __forceinline__ f32x4 mf(h8 a, h8 b, f32x4 c) {
  return __builtin_amdgcn_mfma_f32_16x16x32_f16(a, b, c, 0, 0, 0);
}
#define SPLAT(v) ((f32x4){(v), (v), (v), (v)})

__device__ __forceinline__ void cell_ew(f32x4 g0, f32x4 g1, f32x4 g2, f32x4 g3,
                                        f32x4& c, _Float16* outbuf,
                                        int quad, int r16, int wv) {
  #pragma unroll
  for (int r = 0; r < 4; r++) {
    float gi = sigf(g0[r]);
    float gf = sigf(g1[r]);
    float gg = tanhf_(g2[r]);
    float go = sigf(g3[r]);
    c[r] = fmaf(gf, c[r], gi * gg);
    outbuf[(quad * 4 + r) * HPAD + wv * 16 + r16] = (_Float16)(go * tanhf_(c[r]));
  }
}

// layers 1..3: input-part MFMAs chained onto precomputed acc (bias+rec), then ew
__device__ __forceinline__ void fireH(const h8 (&w)[16], h8 ai0, h8 ai1,
                                      const f32x4 (&ac)[4], f32x4& c,
                                      _Float16* outbuf, int quad, int r16, int wv) {
  f32x4 g0 = mf(ai1, w[1],  mf(ai0, w[0],  ac[0]));
  f32x4 g1 = mf(ai1, w[5],  mf(ai0, w[4],  ac[1]));
  f32x4 g2 = mf(ai1, w[9],  mf(ai0, w[8],  ac[2]));
  f32x4 g3 = mf(ai1, w[13], mf(ai0, w[12], ac[3]));
  cell_ew(g0, g1, g2, g3, c, outbuf, quad, r16, wv);
}
// precompute acc = bias + Whh*h (rec frags kt2/3) for the NEXT timestep
__device__ __forceinline__ void precH(const h8 (&w)[16], h8 ar0, h8 ar1,
                                      f32x4 b, f32x4 (&ac)[4]) {
  ac[0] = mf(ar1, w[3],  mf(ar0, w[2],  SPLAT(b[0])));
  ac[1] = mf(ar1, w[7],  mf(ar0, w[6],  SPLAT(b[1])));
  ac[2] = mf(ar1, w[11], mf(ar0, w[10], SPLAT(b[2])));
  ac[3] = mf(ar1, w[15], mf(ar0, w[14], SPLAT(b[3])));
}
// layer 0: x-part (1 k-tile) onto precomputed acc
__device__ __forceinline__ void fire0(const h8 (&w)[12], h8 ax,
                                      const f32x4 (&ac)[4], f32x4& c,
                                      _Float16* outbuf, int quad, int r16, int wv) {
  f32x4 g0 = mf(ax, w[0], ac[0]);
  f32x4 g1 = mf(ax, w[3], ac[1]);
  f32x4 g2 = mf(ax, w[6], ac[2]);
  f32x4 g3 = mf(ax, w[9], ac[3]);
  cell_ew(g0, g1, g2, g3, c, outbuf, quad, r16, wv);
}
__device__ __forceinline__ void prec0(const h8 (&w)[12], h8 ar0, h8 ar1,
                                      f32x4 b, f32x4 (&ac)[4]) {
  ac[0] = mf(ar1, w[2],  mf(ar0, w[1],  SPLAT(b[0])));
  ac[1] = mf(ar1, w[5],  mf(ar0, w[4],  SPLAT(b[1])));
  ac[2] = mf(ar1, w[8],  mf(ar0, w[7],  SPLAT(b[2])));
  ac[3] = mf(ar1, w[11], mf(ar0, w[10], SPLAT(b[3])));
}
__device__ __forceinline__ void readA(const _Float16* buf, int r16, int quad,
                                      h8& a0, h8& a1) {
  a0 = *(const h8*)(buf + r16 * HPAD + quad * 8);
  a1 = *(const h8*)(buf + r16 * HPAD + 32 + quad * 8);
}

// ---------------------------------------------------------------------------
// Main kernel: 128 blocks x 256 threads (4 waves); block owns batch
// [16b,16b+16); wave wv owns hidden cols [16wv,16wv+16) of every layer.
// ---------------------------------------------------------------------------
__global__ void __launch_bounds__(256, 1)
lstm_main(const float* __restrict__ X,
          const float* __restrict__ encb,
          const float* __restrict__ decb,
          const float* __restrict__ linb,
          const h8* __restrict__ WQ,
          float* __restrict__ out) {
  __shared__ _Float16 Hb[NL][2][16][HPAD];   // 18432 B
  __shared__ _Float16 Xb[2][16][XPAD];       // 2560 B

  const int tid  = threadIdx.x;
  const int wv   = tid >> 6;
  const int lane = tid & 63;
  const int quad = lane >> 4;
  const int r16  = lane & 15;
  const int bbase = blockIdx.x * 16;

  // zero LDS (h0 = 0; pad cols of Xb must stay 0)
  {
    float* p = (float*)&Hb[0][0][0][0];
    for (int i = tid; i < (int)(NL * 2 * 16 * HPAD / 2); i += 256) p[i] = 0.0f;
    float* px = (float*)&Xb[0][0][0];
    for (int i = tid; i < (int)(2 * 16 * XPAD / 2); i += 256) px[i] = 0.0f;
  }
  // preload x[0] into Xb[0]
  if (tid < 96) {
    const int m = tid / NIN, i = tid - m * NIN;
    Xb[0][m][i] = (_Float16)X[((size_t)0 * BATCH + bbase + m) * NIN + i];
  }

  // ---- encoder weights -> registers (per-layer arrays, constant indexing) --
  h8 w0[12], w1[16], w2[16], w3[16];
  #pragma unroll
  for (int f = 0; f < 12; f++) w0[f] = WQ[((f)      * 4 + wv) * 64 + lane];
  #pragma unroll
  for (int f = 0; f < 16; f++) w1[f] = WQ[((12 + f) * 4 + wv) * 64 + lane];
  #pragma unroll
  for (int f = 0; f < 16; f++) w2[f] = WQ[((28 + f) * 4 + wv) * 64 + lane];
  #pragma unroll
  for (int f = 0; f < 16; f++) w3[f] = WQ[((44 + f) * 4 + wv) * 64 + lane];

  // enc biases (per-gate scalars for this lane's hidden col)
  f32x4 b0, b1, b2, b3;
  #pragma unroll
  for (int q = 0; q < 4; q++) {
    b0[q] = encb[0 * 256 + q * 64 + wv * 16 + r16];
    b1[q] = encb[1 * 256 + q * 64 + wv * 16 + r16];
    b2[q] = encb[2 * 256 + q * 64 + wv * 16 + r16];
    b3[q] = encb[3 * 256 + q * 64 + wv * 16 + r16];
  }

  // persistent accumulators = bias + rec-partial; h[-1]=0 -> just bias
  f32x4 ac0[4], ac1[4], ac2[4], ac3[4];
  #pragma unroll
  for (int q = 0; q < 4; q++) {
    ac0[q] = SPLAT(b0[q]); ac1[q] = SPLAT(b1[q]);
    ac2[q] = SPLAT(b2[q]); ac3[q] = SPLAT(b3[q]);
  }

  f32x4 cs0 = SPLAT(0.f), cs1 = SPLAT(0.f), cs2 = SPLAT(0.f), cs3 = SPLAT(0.f);

  // projection fragments (wave 0)
  h8 lwf0 = {}, lwf1 = {};
  float lbv = 0.0f;
  if (wv == 0) {
    lwf0 = WQ[PACK_H8 + lane];
    lwf1 = WQ[PACK_H8 + 64 + lane];
    lbv  = (r16 < NIN) ? linb[r16] : 0.0f;
  }

  __syncthreads();

  // ------------------------------- encoder --------------------------------
  #pragma unroll 1
  for (int t = 0; t < S_LEN; t++) {
    const int cur = t & 1, prv = cur ^ 1;
    // ---- interval 0: layer 0 fire; precompute acc3 from h3[t-1] ----
    {
      h8 ax = *(const h8*)(&Xb[cur][0][0] + r16 * XPAD + quad * 8);
      h8 ar0, ar1;
      readA(&Hb[3][prv][0][0], r16, quad, ar0, ar1);
      // prefetch x[t+1] (off critical path)
      float xv = 0.0f; int pm = 0, pi = 0;
      const bool doPf = (tid < 96) && (t + 1 < S_LEN);
      if (doPf) {
        pm = tid / NIN; pi = tid - pm * NIN;
        xv = X[((size_t)(t + 1) * BATCH + bbase + pm) * NIN + pi];
      }
      fire0(w0, ax, ac0, cs0, &Hb[0][cur][0][0], quad, r16, wv);
      precH(w3, ar0, ar1, b3, ac3);
      __syncthreads();
      // ---- interval 1: layer 1 fire; precompute acc0 (same frags) ----
      h8 ai0, ai1;
      readA(&Hb[0][cur][0][0], r16, quad, ai0, ai1);
      fireH(w1, ai0, ai1, ac1, cs1, &Hb[1][cur][0][0], quad, r16, wv);
      prec0(w0, ai0, ai1, b0, ac0);
      if (doPf) Xb[prv][pm][pi] = (_Float16)xv;   // (t+1)&1 == prv
      __syncthreads();
      // ---- interval 2: layer 2 fire; precompute acc1 ----
      readA(&Hb[1][cur][0][0], r16, quad, ai0, ai1);
      fireH(w2, ai0, ai1, ac2, cs2, &Hb[2][cur][0][0], quad, r16, wv);
      precH(w1, ai0, ai1, b1, ac1);
      __syncthreads();
      // ---- interval 3: layer 3 fire (acc3 from interval 0); precompute acc2
      readA(&Hb[2][cur][0][0], r16, quad, ai0, ai1);
      fireH(w3, ai0, ai1, ac3, cs3, &Hb[3][cur][0][0], quad, r16, wv);
      precH(w2, ai0, ai1, b2, ac2);
      __syncthreads();
    }
  }

  // -------------------- switch to decoder weights/biases ------------------
  #pragma unroll
  for (int f = 0; f < 12; f++) w0[f] = WQ[((FRAGS_HALF + f)      * 4 + wv) * 64 + lane];
  #pragma unroll
  for (int f = 0; f < 16; f++) w1[f] = WQ[((FRAGS_HALF + 12 + f) * 4 + wv) * 64 + lane];
  #pragma unroll
  for (int f = 0; f < 16; f++) w2[f] = WQ[((FRAGS_HALF + 28 + f) * 4 + wv) * 64 + lane];
  #pragma unroll
  for (int f = 0; f < 16; f++) w3[f] = WQ[((FRAGS_HALF + 44 + f) * 4 + wv) * 64 + lane];
  #pragma unroll
  for (int q = 0; q < 4; q++) {
    b0[q] = decb[0 * 256 + q * 64 + wv * 16 + r16];
    b1[q] = decb[1 * 256 + q * 64 + wv * 16 + r16];
    b2[q] = decb[2 * 256 + q * 64 + wv * 16 + r16];
    b3[q] = decb[3 * 256 + q * 64 + wv * 16 + r16];
  }
  // seed all accs with dec weights + encoder-final h (in Hb[*][1])
  {
    h8 s0, s1;
    readA(&Hb[0][1][0][0], r16, quad, s0, s1); prec0(w0, s0, s1, b0, ac0);
    readA(&Hb[1][1][0][0], r16, quad, s0, s1); precH(w1, s0, s1, b1, ac1);
    readA(&Hb[2][1][0][0], r16, quad, s0, s1); precH(w2, s0, s1, b2, ac2);
    readA(&Hb[3][1][0][0], r16, quad, s0, s1); precH(w3, s0, s1, b3, ac3);
  }

  // ------------------------------- decoder --------------------------------
  #pragma unroll 1
  for (int t = 0; t < TLEN; t++) {
    const int cur = t & 1, prv = cur ^ 1;
    // interval 0: layer 0 from Xb[prv] (x[119] for t=0, else proj feedback)
    {
      h8 ax = *(const h8*)(&Xb[prv][0][0] + r16 * XPAD + quad * 8);
      fire0(w0, ax, ac0, cs0, &Hb[0][cur][0][0], quad, r16, wv);
      __syncthreads();
      h8 ai0, ai1;
      readA(&Hb[0][cur][0][0], r16, quad, ai0, ai1);
      fireH(w1, ai0, ai1, ac1, cs1, &Hb[1][cur][0][0], quad, r16, wv);
      prec0(w0, ai0, ai1, b0, ac0);
      __syncthreads();
      readA(&Hb[1][cur][0][0], r16, quad, ai0, ai1);
      fireH(w2, ai0, ai1, ac2, cs2, &Hb[2][cur][0][0], quad, r16, wv);
      precH(w1, ai0, ai1, b1, ac1);
      __syncthreads();
      readA(&Hb[2][cur][0][0], r16, quad, ai0, ai1);
      fireH(w3, ai0, ai1, ac3, cs3, &Hb[3][cur][0][0], quad, r16, wv);
      precH(w2, ai0, ai1, b2, ac2);
      __syncthreads();
      // proj interval: all waves precompute acc3 from h3[t]; wave 0 projects
      h8 ar0, ar1;
      readA(&Hb[3][cur][0][0], r16, quad, ar0, ar1);
      precH(w3, ar0, ar1, b3, ac3);
      if (wv == 0) {
        f32x4 ap = SPLAT(lbv);
        ap = mf(ar0, lwf0, ap);
        ap = mf(ar1, lwf1, ap);
        if (r16 < NIN) {
          #pragma unroll
          for (int r = 0; r < 4; r++) {
            const int m = quad * 4 + r;
            out[((size_t)t * BATCH + bbase + m) * NIN + r16] = ap[r];
            Xb[cur][m][r16] = (_Float16)ap[r];
          }
        }
      }
      __syncthreads();
    }
  }
}

// ---------------------------------------------------------------------------
extern "C" void kernel_launch(void* const* d_in, const int* in_sizes, int n_in,
                              void* d_out, int out_size, void* d_ws, size_t ws_size,
                              hipStream_t stream) {
  const float* X     = (const float*)d_in[0];
  const float* eWih0 = (const float*)d_in[1];
  const float* eWih  = (const float*)d_in[2];
  const float* eWhh  = (const float*)d_in[3];
  const float* eb    = (const float*)d_in[4];
  const float* dWih0 = (const float*)d_in[5];
  const float* dWih  = (const float*)d_in[6];
  const float* dWhh  = (const float*)d_in[7];
  const float* db    = (const float*)d_in[8];
  const float* lW    = (const float*)d_in[9];
  const float* lb    = (const float*)d_in[10];

  _Float16* wq = (_Float16*)d_ws;

  prep_weights<<<(NPACK + 255) / 256, 256, 0, stream>>>(
      eWih0, eWih, eWhh, dWih0, dWih, dWhh, lW, wq);

  lstm_main<<<BATCH / 16, 256, 0, stream>>>(
      X, eb, db, lb, (const h8*)wq, (float*)d_out);
}

// Round 5
// 579.417 us; speedup vs baseline: 10.6673x; 1.0092x over previous
//
#include <hip/hip_runtime.h>

// ---------------------------------------------------------------------------
// Round 5: encoder wavefront pipeline (wave l = layer l; 480 -> 123 intervals)
// + decoder projection fused into layer-0 interval (5 -> 4 intervals/step).
// Encoder h stored k-permuted (pi(c) = 4*(c&15)+(c>>4)) so each lane's 4
// h-outputs are one ds_write_b64; weight pack pre-permutes B rows to match.
// Decoder unchanged col-sliced scheme with precomputed recurrent partials.
// ---------------------------------------------------------------------------

#define S_LEN 120
#define BATCH 2048
#define NIN   6
#define H     64
#define NL    4
#define TLEN  120

#define HPAD 72            // row stride in halves (144 B)

#define FRAGS_HALF 60      // decoder col-sliced: 12 (layer0) + 3*16
#define PACK_H8    (2 * FRAGS_HALF * 4 * 64)
#define PROJ_H8    (2 * 64)
#define NPACK      ((PACK_H8 + PROJ_H8) * 8)   // 246784 fp16 elements
#define EPACK_EL   (256 * 64 * 8)              // encoder pipeline pack
#define NTOT       (NPACK + EPACK_EL)          // 377856 elements (~756 KB)

#define PERM(kk) ((((kk) & 3) << 4) | ((kk) >> 2))   // pi^-1
#define PI(c)    ((((c) & 15) << 2) | ((c) >> 4))    // pi

typedef _Float16 h8    __attribute__((ext_vector_type(8)));
typedef _Float16 h4    __attribute__((ext_vector_type(4)));
typedef float    f32x4 __attribute__((ext_vector_type(4)));

// ---------------------------------------------------------------------------
// Weight pack:
//  [0, PACK_H8)            decoder/col-sliced frags (enc half unused now)
//  [PACK_H8, +PROJ_H8)     linW as A-layout frags (m=feature, k=hidden plain)
//  [NPACK/8, +256*64)      encoder pipeline: fe = l*64 + nt*4 + kt, B rows
//                          k-permuted for hidden dims (PERM), plain for x.
// ---------------------------------------------------------------------------
__global__ void prep_weights(const float* __restrict__ eWih0,
                             const float* __restrict__ eWih,
                             const float* __restrict__ eWhh,
                             const float* __restrict__ dWih0,
                             const float* __restrict__ dWih,
                             const float* __restrict__ dWhh,
                             const float* __restrict__ linW,
                             _Float16* __restrict__ wq) {
  int idx = blockIdx.x * blockDim.x + threadIdx.x;
  if (idx >= NTOT) return;

  if (idx >= NPACK) {                      // ---- encoder pipeline pack ----
    int p    = idx - NPACK;
    int j    = p & 7;
    int lane = (p >> 3) & 63;
    int fe   = p >> 9;
    int kt   = fe & 3, nt = (fe >> 2) & 15, l = fe >> 6;
    int g    = nt * 16 + (lane & 15);
    int koff = ((lane >> 4) << 3) + j;     // 0..31
    float v = 0.0f;
    if (l == 0) {
      if (kt == 0)      v = (koff < NIN) ? eWih0[g * NIN + koff] : 0.0f;
      else if (kt == 1) v = 0.0f;          // zero tile (uniform shape)
      else { int kk = (kt - 2) * 32 + koff; v = eWhh[g * H + PERM(kk)]; }
    } else {
      if (kt < 2) { int kk = kt * 32 + koff;
                    v = eWih[((l - 1) * 256 + g) * H + PERM(kk)]; }
      else        { int kk = (kt - 2) * 32 + koff;
                    v = eWhh[(l * 256 + g) * H + PERM(kk)]; }
    }
    wq[idx] = (_Float16)v;
    return;
  }

  if (idx >= PACK_H8 * 8) {                // ---- linW A-layout frags ----
    int p    = idx - PACK_H8 * 8;
    int j    = p & 7;
    int lane = (p >> 3) & 63;
    int fr   = p >> 9;                     // 0,1 (k tiles)
    int m    = lane & 15;                  // feature
    int k    = fr * 32 + ((lane >> 4) << 3) + j;
    wq[idx] = (_Float16)((m < NIN) ? linW[m * H + k] : 0.0f);
    return;
  }

  // ---- col-sliced pack (decoder; enc half kept for layout stability) ----
  const int j    = idx & 7;
  const int lane = (idx >> 3) & 63;
  const int wv   = (idx >> 9) & 3;
  const int fh   = idx >> 11;
  const int f    = fh % FRAGS_HALF;
  const int half = fh / FRAGS_HALF;
  const float* Wi0 = half ? dWih0 : eWih0;
  const float* Wi  = half ? dWih  : eWih;
  const float* Wh  = half ? dWhh  : eWhh;
  int l, q, kt;
  if (f < 12) { l = 0; q = f / 3; kt = f % 3; }
  else        { int ff = f - 12; l = 1 + ff / 16; ff %= 16; q = ff / 4; kt = ff % 4; }
  const int g    = q * 64 + wv * 16 + (lane & 15);
  const int k_in = ((lane >> 4) << 3) + j;
  float v;
  if (l == 0) {
    if (kt == 0) v = (k_in < NIN) ? Wi0[g * NIN + k_in] : 0.0f;
    else         v = Wh[g * H + (kt - 1) * 32 + k_in];
  } else {
    if (kt < 2) v = Wi[((l - 1) * 256 + g) * H + kt * 32 + k_in];
    else        v = Wh[(l * 256 + g) * H + (kt - 2) * 32 + k_in];
  }
  wq[idx] = (_Float16)v;
}

// ---------------------------------------------------------------------------
__device__ __forceinline__ float rcpf(float x) { return __builtin_amdgcn_rcpf(x); }
__device__ __forceinline__ float sigf(float x) { return rcpf(1.0f + __expf(-x)); }
__device__ __forceinline__ float tanhf_(float x) {
  float e = __expf(2.0f * x);
  return 1.0f - 2.0f * rcpf(e + 1.0f);
}
__device__ __forceinline__ f32x4 mf(h8 a, h8 b, f32x4 c) {
  return __builtin_amdgcn_mfma_f32_16x16x32_f16(a, b, c, 0, 0, 0);
}
#define SPLAT(v) ((f32x4){(v), (v), (v), (v)})

__device__ __forceinline__ void cell_ew(f32x4 g0, f32x4 g1, f32x4 g2, f32x4 g3,
                                        f32x4& c, _Float16* outbuf,
                                        int quad, int r16, int wv) {
  #pragma unroll
  for (int r = 0; r < 4; r++) {
    float gi = sigf(g0[r]);
    float gf = sigf(g1[r]);
    float gg = tanhf_(g2[r]);
    float go = sigf(g3[r]);
    c[r] = fmaf(gf, c[r], gi * gg);
    outbuf[(quad * 4 + r) * HPAD + wv * 16 + r16] = (_Float16)(go * tanhf_(c[r]));
  }
}
__device__ __forceinline__ void fireH(const h8 (&w)[16], h8 ai0, h8 ai1,
                                      const f32x4 (&ac)[4], f32x4& c,
                                      _Float16* outbuf, int quad, int r16, int wv) {
  f32x4 g0 = mf(ai1, w[1],  mf(ai0, w[0],  ac[0]));
  f32x4 g1 = mf(ai1, w[5],  mf(ai0, w[4],  ac[1]));
  f32x4 g2 = mf(ai1, w[9],  mf(ai0, w[8],  ac[2]));
  f32x4 g3 = mf(ai1, w[13], mf(ai0, w[12], ac[3]));
  cell_ew(g0, g1, g2, g3, c, outbuf, quad, r16, wv);
}
__device__ __forceinline__ void precH(const h8 (&w)[16], h8 ar0, h8 ar1,
                                      f32x4 b, f32x4 (&ac)[4]) {
  ac[0] = mf(ar1, w[3],  mf(ar0, w[2],  SPLAT(b[0])));
  ac[1] = mf(ar1, w[7],  mf(ar0, w[6],  SPLAT(b[1])));
  ac[2] = mf(ar1, w[11], mf(ar0, w[10], SPLAT(b[2])));
  ac[3] = mf(ar1, w[15], mf(ar0, w[14], SPLAT(b[3])));
}
__device__ __forceinline__ void fire0(const h8 (&w)[12], h8 ax,
                                      const f32x4 (&ac)[4], f32x4& c,
                                      _Float16* outbuf, int quad, int r16, int wv) {
  f32x4 g0 = mf(ax, w[0], ac[0]);
  f32x4 g1 = mf(ax, w[3], ac[1]);
  f32x4 g2 = mf(ax, w[6], ac[2]);
  f32x4 g3 = mf(ax, w[9], ac[3]);
  cell_ew(g0, g1, g2, g3, c, outbuf, quad, r16, wv);
}
__device__ __forceinline__ void prec0(const h8 (&w)[12], h8 ar0, h8 ar1,
                                      f32x4 b, f32x4 (&ac)[4]) {
  ac[0] = mf(ar1, w[2],  mf(ar0, w[1],  SPLAT(b[0])));
  ac[1] = mf(ar1, w[5],  mf(ar0, w[4],  SPLAT(b[1])));
  ac[2] = mf(ar1, w[8],  mf(ar0, w[7],  SPLAT(b[2])));
  ac[3] = mf(ar1, w[11], mf(ar0, w[10], SPLAT(b[3])));
}
__device__ __forceinline__ void readA(const _Float16* buf, int r16, int quad,
                                      h8& a0, h8& a1) {
  a0 = *(const h8*)(buf + r16 * HPAD + quad * 8);
  a1 = *(const h8*)(buf + r16 * HPAD + 32 + quad * 8);
}

// ---------------------------------------------------------------------------
__global__ void __launch_bounds__(256, 1)
lstm_main(const float* __restrict__ X,
          const float* __restrict__ encb,
          const float* __restrict__ decb,
          const float* __restrict__ linb,
          const h8* __restrict__ WQ,
          float* __restrict__ out) {
  __shared__ _Float16 Hb[NL][2][16][HPAD];   // 18432 B
  __shared__ _Float16 Xb[2][16][HPAD];       //  4608 B (cols >=6 stay zero)
  __shared__ float    Cx[NL][16][68];        // 17408 B (one-time c hand-off)

  const int tid   = threadIdx.x;
  const int wv    = tid >> 6;
  const int lane  = tid & 63;
  const int quad  = lane >> 4;
  const int r16   = lane & 15;
  const int bbase = blockIdx.x * 16;

  // zero Hb + Xb
  {
    float* p = (float*)&Hb[0][0][0][0];
    for (int i = tid; i < (int)(NL * 2 * 16 * HPAD / 2); i += 256) p[i] = 0.0f;
    float* px = (float*)&Xb[0][0][0];
    for (int i = tid; i < (int)(2 * 16 * HPAD / 2); i += 256) px[i] = 0.0f;
  }
  if (tid < 96) {
    const int m = tid / NIN, i = tid - m * NIN;
    Xb[0][m][i] = (_Float16)X[((size_t)0 * BATCH + bbase + m) * NIN + i];
  }

  // ======================= ENCODER: wavefront pipeline =====================
  // wave wv = layer wv; full-layer weights (16 n-tiles x 4 k-tiles) in regs.
  h8 we[16][4];
  #pragma unroll
  for (int nt = 0; nt < 16; nt++)
    #pragma unroll
    for (int kt = 0; kt < 4; kt++)
      we[nt][kt] = WQ[(PACK_H8 + PROJ_H8) + ((wv * 64 + nt * 4 + kt) * 64 + lane)];

  float ben[16];
  #pragma unroll
  for (int nt = 0; nt < 16; nt++) ben[nt] = encb[wv * 256 + nt * 16 + r16];

  f32x4 ce[4];
  #pragma unroll
  for (int ct = 0; ct < 4; ct++) ce[ct] = SPLAT(0.f);

  __syncthreads();

  #pragma unroll 1
  for (int i = 0; i < S_LEN + NL - 1; i++) {     // 123 intervals
    const int p = i & 1;
    const bool active = (i >= wv) && (i - wv < S_LEN);
    if (active) {
      const _Float16* inb = (wv == 0) ? &Xb[p][0][0] : &Hb[wv - 1][p ^ 1][0][0];
      const _Float16* rcb = &Hb[wv][p ^ 1][0][0];
      h8 ai0 = *(const h8*)(inb + r16 * HPAD + quad * 8);
      h8 ai1 = *(const h8*)(inb + r16 * HPAD + 32 + quad * 8);
      h8 ar0 = *(const h8*)(rcb + r16 * HPAD + quad * 8);
      h8 ar1 = *(const h8*)(rcb + r16 * HPAD + 32 + quad * 8);

      // x prefetch (wave 0, off critical path)
      float pf0 = 0.f, pf1 = 0.f;
      const bool doPf = (wv == 0) && (lane < 48) && (i + 1 < S_LEN);
      if (doPf) {
        const float* xs = X + ((size_t)(i + 1) * BATCH + bbase) * NIN;
        pf0 = xs[lane * 2];
        pf1 = xs[lane * 2 + 1];
      }

      f32x4 acc[16];
      #pragma unroll
      for (int nt = 0; nt < 16; nt++) {
        f32x4 a = SPLAT(ben[nt]);
        a = mf(ai0, we[nt][0], a);
        a = mf(ai1, we[nt][1], a);
        a = mf(ar0, we[nt][2], a);
        a = mf(ar1, we[nt][3], a);
        acc[nt] = a;
      }

      _Float16* wb = &Hb[wv][p][0][0];
      #pragma unroll
      for (int r = 0; r < 4; r++) {            // r-major: low liveness
        h4 hv;
        #pragma unroll
        for (int ct = 0; ct < 4; ct++) {
          float gi = sigf(acc[ct][r]);
          float gf = sigf(acc[4 + ct][r]);
          float gg = tanhf_(acc[8 + ct][r]);
          float go = sigf(acc[12 + ct][r]);
          ce[ct][r] = fmaf(gf, ce[ct][r], gi * gg);
          hv[ct] = (_Float16)(go * tanhf_(ce[ct][r]));
        }
        // permuted write: cols {16ct+r16} land at 4*r16..4*r16+3
        *(h4*)(wb + (quad * 4 + r) * HPAD + 4 * r16) = hv;
      }

      if (doPf) {
        int e0 = lane * 2, e1 = e0 + 1;
        Xb[p ^ 1][e0 / NIN][e0 % NIN] = (_Float16)pf0;
        Xb[p ^ 1][e1 / NIN][e1 % NIN] = (_Float16)pf1;
      }
    }
    __syncthreads();
  }

  // ===================== transition: encoder -> decoder ====================
  // stash c (wave wv holds layer wv, all 64 cols)
  #pragma unroll
  for (int ct = 0; ct < 4; ct++)
    #pragma unroll
    for (int r = 0; r < 4; r++)
      Cx[wv][quad * 4 + r][ct * 16 + r16] = ce[ct][r];

  // unpermute final h of each layer into Hb[l][1] (plain layout)
  float hreg[16];
  #pragma unroll
  for (int u = 0; u < 16; u++) {
    int i2 = tid + u * 256;
    int l = i2 >> 10, m = (i2 >> 6) & 15, c = i2 & 63;
    hreg[u] = (float)Hb[l][(l + 1) & 1][m][PI(c)];
  }
  __syncthreads();
  #pragma unroll
  for (int u = 0; u < 16; u++) {
    int i2 = tid + u * 256;
    int l = i2 >> 10, m = (i2 >> 6) & 15, c = i2 & 63;
    Hb[l][1][m][c] = (_Float16)hreg[u];
  }
  __syncthreads();

  // decoder c-state slices
  f32x4 cs0, cs1, cs2, cs3;
  #pragma unroll
  for (int r = 0; r < 4; r++) {
    cs0[r] = Cx[0][quad * 4 + r][wv * 16 + r16];
    cs1[r] = Cx[1][quad * 4 + r][wv * 16 + r16];
    cs2[r] = Cx[2][quad * 4 + r][wv * 16 + r16];
    cs3[r] = Cx[3][quad * 4 + r][wv * 16 + r16];
  }

  // decoder weights (col-sliced, dec half) + biases
  h8 w0[12], w1[16], w2[16], w3[16];
  #pragma unroll
  for (int f = 0; f < 12; f++) w0[f] = WQ[((FRAGS_HALF + f)      * 4 + wv) * 64 + lane];
  #pragma unroll
  for (int f = 0; f < 16; f++) w1[f] = WQ[((FRAGS_HALF + 12 + f) * 4 + wv) * 64 + lane];
  #pragma unroll
  for (int f = 0; f < 16; f++) w2[f] = WQ[((FRAGS_HALF + 28 + f) * 4 + wv) * 64 + lane];
  #pragma unroll
  for (int f = 0; f < 16; f++) w3[f] = WQ[((FRAGS_HALF + 44 + f) * 4 + wv) * 64 + lane];

  f32x4 b0, b1, b2, b3;
  #pragma unroll
  for (int q = 0; q < 4; q++) {
    b0[q] = decb[0 * 256 + q * 64 + wv * 16 + r16];
    b1[q] = decb[1 * 256 + q * 64 + wv * 16 + r16];
    b2[q] = decb[2 * 256 + q * 64 + wv * 16 + r16];
    b3[q] = decb[3 * 256 + q * 64 + wv * 16 + r16];
  }

  // projection A-frags + per-row bias (all waves; redundant compute)
  h8 lwA0 = WQ[PACK_H8 + lane];
  h8 lwA1 = WQ[PACK_H8 + 64 + lane];
  f32x4 lbq;
  #pragma unroll
  for (int r = 0; r < 4; r++)
    lbq[r] = (quad * 4 + r < NIN) ? linb[quad * 4 + r] : 0.0f;

  // seed accumulators from encoder-final h (ac3 comes from interval A)
  f32x4 ac0[4], ac1[4], ac2[4], ac3[4];
  {
    h8 s0, s1;
    readA(&Hb[0][1][0][0], r16, quad, s0, s1); prec0(w0, s0, s1, b0, ac0);
    readA(&Hb[1][1][0][0], r16, quad, s0, s1); precH(w1, s0, s1, b1, ac1);
    readA(&Hb[2][1][0][0], r16, quad, s0, s1); precH(w2, s0, s1, b2, ac2);
  }
  __syncthreads();

  // ============================== DECODER ================================
  #pragma unroll 1
  for (int t = 0; t < TLEN; t++) {
    const int cur = t & 1, prv = cur ^ 1;
    // ---- interval A: proj(h3[t-1]) + layer-0 fire + acc3 precompute ----
    {
      h8 ar0, ar1;
      readA(&Hb[3][prv][0][0], r16, quad, ar0, ar1);
      h8 ax;
      if (t == 0) {
        ax = *(const h8*)(&Xb[1][0][0] + r16 * HPAD + quad * 8);  // x[119]
      } else {
        f32x4 ap = lbq;
        ap = mf(lwA0, ar0, ap);          // A = linW (m=feature), B = h3 (n=batch)
        ap = mf(lwA1, ar1, ap);
        if (wv == 0) {
          #pragma unroll
          for (int r = 0; r < 4; r++) {
            const int fm = quad * 4 + r;
            if (fm < NIN)
              out[((size_t)(t - 1) * BATCH + bbase + r16) * NIN + fm] = ap[r];
          }
        }
        // transpose (feature,batch)->(batch,feature) via shfl; batch=lane&15
        float x0 = __shfl(ap[0], r16);
        float x1 = __shfl(ap[1], r16);
        float x2 = __shfl(ap[2], r16);
        float x3 = __shfl(ap[3], r16);
        float x4 = __shfl(ap[0], 16 + r16);
        float x5 = __shfl(ap[1], 16 + r16);
        h8 xa = {};
        xa[0] = (_Float16)x0; xa[1] = (_Float16)x1; xa[2] = (_Float16)x2;
        xa[3] = (_Float16)x3; xa[4] = (_Float16)x4; xa[5] = (_Float16)x5;
        h8 zz = {};
        ax = (quad == 0) ? xa : zz;
      }
      precH(w3, ar0, ar1, b3, ac3);
      fire0(w0, ax, ac0, cs0, &Hb[0][cur][0][0], quad, r16, wv);
      __syncthreads();
    }
    // ---- interval B ----
    {
      h8 ai0, ai1;
      readA(&Hb[0][cur][0][0], r16, quad, ai0, ai1);
      fireH(w1, ai0, ai1, ac1, cs1, &Hb[1][cur][0][0], quad, r16, wv);
      prec0(w0, ai0, ai1, b0, ac0);
      __syncthreads();
    }
    // ---- interval C ----
    {
      h8 ai0, ai1;
      readA(&Hb[1][cur][0][0], r16, quad, ai0, ai1);
      fireH(w2, ai0, ai1, ac2, cs2, &Hb[2][cur][0][0], quad, r16, wv);
      precH(w1, ai0, ai1, b1, ac1);
      __syncthreads();
    }
    // ---- interval D ----
    {
      h8 ai0, ai1;
      readA(&Hb[2][cur][0][0], r16, quad, ai0, ai1);
      fireH(w3, ai0, ai1, ac3, cs3, &Hb[3][cur][0][0], quad, r16, wv);
      precH(w2, ai0, ai1, b2, ac2);
      __syncthreads();
    }
  }

  // epilogue: out[TLEN-1] from h3 of last step (parity (TLEN-1)&1 = 1)
  if (wv == 0) {
    h8 ar0, ar1;
    readA(&Hb[3][1][0][0], r16, quad, ar0, ar1);
    f32x4 ap = lbq;
    ap = mf(lwA0, ar0, ap);
    ap = mf(lwA1, ar1, ap);
    #pragma unroll
    for (int r = 0; r < 4; r++) {
      const int fm = quad * 4 + r;
      if (fm < NIN)
        out[((size_t)(TLEN - 1) * BATCH + bbase + r16) * NIN + fm] = ap[r];
    }
  }
}

// ---------------------------------------------------------------------------
extern "C" void kernel_launch(void* const* d_in, const int* in_sizes, int n_in,
                              void* d_out, int out_size, void* d_ws, size_t ws_size,
                              hipStream_t stream) {
  const float* X     = (const float*)d_in[0];
  const float* eWih0 = (const float*)d_in[1];
  const float* eWih  = (const float*)d_in[2];
  const float* eWhh  = (const float*)d_in[3];
  const float* eb    = (const float*)d_in[4];
  const float* dWih0 = (const float*)d_in[5];
  const float* dWih  = (const float*)d_in[6];
  const float* dWhh  = (const float*)d_in[7];
  const float* db    = (const float*)d_in[8];
  const float* lW    = (const float*)d_in[9];
  const float* lb    = (const float*)d_in[10];

  _Float16* wq = (_Float16*)d_ws;   // ~756 KB pack

  prep_weights<<<(NTOT + 255) / 256, 256, 0, stream>>>(
      eWih0, eWih, eWhh, dWih0, dWih, dWhh, lW, wq);

  lstm_main<<<BATCH / 16, 256, 0, stream>>>(
      X, eb, db, lb, (const h8*)wq, (float*)d_out);
}